// Round 1
// baseline (411.927 us; speedup 1.0000x reference)
//
#include <hip/hip_runtime.h>
#include <hip/hip_bf16.h>
#include <stdint.h>

#define N_ROWS 65536
#define N_CLS  1000
#define KPAD   1024
#define FEAT   256
#define MT     64          // rows per block
#define BK     64          // k per iteration
#define NIT    (KPAD/BK)   // 16
#define LDA    72          // padded LDS stride (bf16 elems): 144 B, 16B-aligned, 2-way-bank only
#define LDB    72

typedef short bf16x8 __attribute__((ext_vector_type(8)));
typedef float f32x4  __attribute__((ext_vector_type(4)));

__device__ __forceinline__ ushort f32_to_bf16_rne(float f) {
    union { float f; uint32_t u; } x; x.f = f;
    uint32_t u = x.u + 0x7FFFu + ((x.u >> 16) & 1u);
    return (ushort)(u >> 16);
}

// Prep: centersT[n][c] = bf16(centers[c][n]) padded to KPAD with zeros;
// csq[c] = ||centers[c]||^2 (fp32, zero-padded); zero d_out.
__global__ __launch_bounds__(256) void prep_kernel(const float* __restrict__ centers,
                                                   ushort* __restrict__ centersT,
                                                   float* __restrict__ csq,
                                                   float* __restrict__ out) {
    const int c = blockIdx.x;     // 0..1023
    const int n = threadIdx.x;    // 0..255
    float v = 0.f;
    if (c < N_CLS) v = centers[(size_t)c * FEAT + n];
    centersT[(size_t)n * KPAD + c] = f32_to_bf16_rne(v);
    float sq = v * v;
    #pragma unroll
    for (int off = 32; off > 0; off >>= 1) sq += __shfl_down(sq, off);
    __shared__ float red[4];
    if ((threadIdx.x & 63) == 0) red[threadIdx.x >> 6] = sq;
    __syncthreads();
    if (threadIdx.x == 0) {
        csq[c] = red[0] + red[1] + red[2] + red[3];
        if (c == 0) out[0] = 0.f;
    }
}

__global__ __launch_bounds__(256) void main_kernel(const int* __restrict__ gt,
                                                   const float* __restrict__ features,
                                                   const ushort* __restrict__ centersT,
                                                   const float* __restrict__ csq,
                                                   float* __restrict__ out) {
    __shared__ ushort As[MT * LDA];     // 9216 B
    __shared__ ushort Bs[FEAT * LDB];   // 36864 B
    __shared__ float  rcS[256];
    __shared__ float  t2S[256];
    __shared__ float  rowcnt[MT];
    __shared__ float  t2row[MT];
    __shared__ float  blockred[4];

    const int tid  = threadIdx.x;
    const int m0   = blockIdx.x * MT;
    const int r    = tid >> 2;       // staging row 0..63
    const int kc   = tid & 3;        // staging k-quarter
    const int lane = tid & 63;
    const int w    = tid >> 6;       // wave 0..3 -> cols w*64
    const int ml   = lane & 15;
    const int quad = lane >> 4;

    f32x4 acc[4][4];
    #pragma unroll
    for (int i = 0; i < 4; i++)
        #pragma unroll
        for (int j = 0; j < 4; j++)
            #pragma unroll
            for (int k = 0; k < 4; k++) acc[i][j][k] = 0.f;

    float rc = 0.f, t2 = 0.f;
    const int* gtrow = gt + (size_t)(m0 + r) * N_CLS;

    for (int it = 0; it < NIT; ++it) {
        const int k0 = it * BK;
        __syncthreads();

        // ---- stage A: gt[m0+r][k0+kc*16 .. +15] -> bf16 LDS; fuse rowcnt/t2 ----
        const int kb = k0 + kc * 16;
        int v[16];
        if (kb + 16 <= N_CLS) {
            const int4* p = (const int4*)(gtrow + kb);
            int4 a0 = p[0], a1 = p[1], a2 = p[2], a3 = p[3];
            v[0]=a0.x; v[1]=a0.y; v[2]=a0.z; v[3]=a0.w;
            v[4]=a1.x; v[5]=a1.y; v[6]=a1.z; v[7]=a1.w;
            v[8]=a2.x; v[9]=a2.y; v[10]=a2.z; v[11]=a2.w;
            v[12]=a3.x; v[13]=a3.y; v[14]=a3.z; v[15]=a3.w;
        } else {
            #pragma unroll
            for (int j = 0; j < 16; j++) {
                int k = kb + j;
                v[j] = (k < N_CLS) ? gtrow[k] : 0;
            }
        }
        // csq for this k-chunk (padded to KPAD, always in-bounds)
        float cs[16];
        {
            const float4* cp = (const float4*)(csq + kb);
            float4 q0 = cp[0], q1 = cp[1], q2 = cp[2], q3 = cp[3];
            cs[0]=q0.x; cs[1]=q0.y; cs[2]=q0.z; cs[3]=q0.w;
            cs[4]=q1.x; cs[5]=q1.y; cs[6]=q1.z; cs[7]=q1.w;
            cs[8]=q2.x; cs[9]=q2.y; cs[10]=q2.z; cs[11]=q2.w;
            cs[12]=q3.x; cs[13]=q3.y; cs[14]=q3.z; cs[15]=q3.w;
        }
        uint32_t u[8];
        #pragma unroll
        for (int j = 0; j < 8; j++) {
            uint32_t lo = (v[2*j]   > 0) ? 0x3F80u : 0u;
            uint32_t hi = (v[2*j+1] > 0) ? 0x3F80u : 0u;
            u[j] = lo | (hi << 16);
        }
        #pragma unroll
        for (int j = 0; j < 16; j++) {
            bool m = v[j] > 0;
            rc += m ? 1.f : 0.f;
            t2 += m ? cs[j] : 0.f;
        }
        {
            uint4* dst = (uint4*)&As[r * LDA + kc * 16];
            dst[0] = make_uint4(u[0], u[1], u[2], u[3]);
            dst[1] = make_uint4(u[4], u[5], u[6], u[7]);
        }

        // ---- stage B: centersT[n][k0..k0+63] -> Bs[n][k] (k-contiguous) ----
        #pragma unroll
        for (int j = 0; j < 8; j++) {
            int g = j * 256 + tid;       // 2048 chunks of 16 B
            int n = g >> 3;
            int kcb = g & 7;
            *(uint4*)&Bs[n * LDB + kcb * 8] =
                *(const uint4*)&centersT[(size_t)n * KPAD + k0 + kcb * 8];
        }

        __syncthreads();

        // ---- MFMA: 2 k-steps of 32, 4x4 tiles of 16x16 per wave ----
        #pragma unroll
        for (int ks = 0; ks < 2; ++ks) {
            const int kk = ks * 32 + quad * 8;
            bf16x8 af[4], bfr[4];
            #pragma unroll
            for (int mt = 0; mt < 4; mt++)
                af[mt] = *(const bf16x8*)&As[(mt * 16 + ml) * LDA + kk];
            #pragma unroll
            for (int nt = 0; nt < 4; nt++)
                bfr[nt] = *(const bf16x8*)&Bs[(w * 64 + nt * 16 + ml) * LDB + kk];
            #pragma unroll
            for (int mt = 0; mt < 4; mt++)
                #pragma unroll
                for (int nt = 0; nt < 4; nt++)
                    acc[mt][nt] = __builtin_amdgcn_mfma_f32_16x16x32_bf16(
                        af[mt], bfr[nt], acc[mt][nt], 0, 0, 0);
        }
    }

    // ---- per-row reductions (rowcnt, t2row) ----
    rcS[tid] = rc;
    t2S[tid] = t2;
    __syncthreads();
    if (tid < MT) {
        rowcnt[tid] = rcS[tid*4] + rcS[tid*4+1] + rcS[tid*4+2] + rcS[tid*4+3];
        t2row[tid]  = t2S[tid*4] + t2S[tid*4+1] + t2S[tid*4+2] + t2S[tid*4+3];
    }
    __syncthreads();

    // ---- epilogue: read features once, fold all three terms ----
    float part = 0.f;
    #pragma unroll
    for (int mt = 0; mt < 4; mt++) {
        #pragma unroll
        for (int nt = 0; nt < 4; nt++) {
            const int n = w * 64 + nt * 16 + ml;
            #pragma unroll
            for (int reg = 0; reg < 4; reg++) {
                const int ri = mt * 16 + quad * 4 + reg;
                const float f = features[(size_t)(m0 + ri) * FEAT + n];
                const float T = acc[mt][nt][reg];
                part += f * (rowcnt[ri] * f - 2.f * T) + t2row[ri] * (1.f / 256.f);
            }
        }
    }
    #pragma unroll
    for (int off = 32; off > 0; off >>= 1) part += __shfl_down(part, off);
    if (lane == 0) blockred[w] = part;
    __syncthreads();
    if (tid == 0)
        atomicAdd(out, (blockred[0] + blockred[1] + blockred[2] + blockred[3]) *
                           (1.f / (float)N_ROWS));
}

extern "C" void kernel_launch(void* const* d_in, const int* in_sizes, int n_in,
                              void* d_out, int out_size, void* d_ws, size_t ws_size,
                              hipStream_t stream) {
    const int*   gt       = (const int*)d_in[0];
    const float* features = (const float*)d_in[1];
    const float* centers  = (const float*)d_in[2];
    float*       out      = (float*)d_out;

    ushort* centersT = (ushort*)d_ws;                                  // 256*1024*2 = 512 KB
    float*  csq      = (float*)((char*)d_ws + (size_t)FEAT * KPAD * 2); // 4 KB

    prep_kernel<<<KPAD, 256, 0, stream>>>(centers, centersT, csq, out);
    main_kernel<<<N_ROWS / MT, 256, 0, stream>>>(gt, features, centersT, csq, out);
}